// Round 1
// baseline (90.166 us; speedup 1.0000x reference)
//
#include <hip/hip_runtime.h>
#include <math.h>

#define NQ 16
#define LAYERS 8

// ---------------------------------------------------------------------------
// Prep: fold the 8 Rot layers for qubits 0,1 into closed-form coefficients.
// ez_q(x) = A + Bc*cos(x) + Bs*sin(x) where, with U = M7*...*M0 (2x2 complex):
//   d0 = |u00|^2-|u10|^2,  d1 = |u01|^2-|u11|^2
//   A = (d0+d1)/2, Bc = (d0-d1)/2, Bs = -(Im(u00*conj(u01)) - Im(u10*conj(u11)))
// Output (d_ws): coef[0] = head_b + w0*A0 + w1*A1
//                coef[1..4] = w0*Bc0, w0*Bs0, w1*Bc1, w1*Bs1
// ---------------------------------------------------------------------------
__global__ void vqc_prep(const float* __restrict__ params,  // [LAYERS][NQ][3]
                         const float* __restrict__ head_w,  // [2]
                         const float* __restrict__ head_b,  // [1]
                         float* __restrict__ coef)          // 5 floats in d_ws
{
    if (threadIdx.x != 0 || blockIdx.x != 0) return;
    float C = head_b[0];
    float K[4];
    for (int q = 0; q < 2; ++q) {
        // U = identity
        float u00r = 1.f, u00i = 0.f, u01r = 0.f, u01i = 0.f;
        float u10r = 0.f, u10i = 0.f, u11r = 1.f, u11i = 0.f;
        for (int l = 0; l < LAYERS; ++l) {
            float phi = params[(l * NQ + q) * 3 + 0];
            float th  = params[(l * NQ + q) * 3 + 1];
            float om  = params[(l * NQ + q) * 3 + 2];
            float ct = cosf(0.5f * th), st = sinf(0.5f * th);
            float ap = -0.5f * (phi + om);   // m00 = e^{i*ap} ct, m11 = e^{-i*ap} ct
            float am =  0.5f * (phi - om);   // m01 = -e^{i*am} st, m10 = e^{-i*am} st
            float c_p = cosf(ap), s_p = sinf(ap);
            float c_m = cosf(am), s_m = sinf(am);
            float m00r =  c_p * ct, m00i =  s_p * ct;
            float m01r = -c_m * st, m01i = -s_m * st;
            float m10r =  c_m * st, m10i = -s_m * st;
            float m11r =  c_p * ct, m11i = -s_p * ct;
            // U = M * U
            float n00r = m00r*u00r - m00i*u00i + m01r*u10r - m01i*u10i;
            float n00i = m00r*u00i + m00i*u00r + m01r*u10i + m01i*u10r;
            float n01r = m00r*u01r - m00i*u01i + m01r*u11r - m01i*u11i;
            float n01i = m00r*u01i + m00i*u01r + m01r*u11i + m01i*u11r;
            float n10r = m10r*u00r - m10i*u00i + m11r*u10r - m11i*u10i;
            float n10i = m10r*u00i + m10i*u00r + m11r*u10i + m11i*u10r;
            float n11r = m10r*u01r - m10i*u01i + m11r*u11r - m11i*u11i;
            float n11i = m10r*u01i + m10i*u01r + m11r*u11i + m11i*u11r;
            u00r = n00r; u00i = n00i; u01r = n01r; u01i = n01i;
            u10r = n10r; u10i = n10i; u11r = n11r; u11i = n11i;
        }
        float d0 = (u00r*u00r + u00i*u00i) - (u10r*u10r + u10i*u10i);
        float d1 = (u01r*u01r + u01i*u01i) - (u11r*u11r + u11i*u11i);
        float A  = 0.5f * (d0 + d1);
        float Bc = 0.5f * (d0 - d1);
        float im0 = u00i*u01r - u00r*u01i;   // Im(u00 * conj(u01))
        float im1 = u10i*u11r - u10r*u11i;   // Im(u10 * conj(u11))
        float Bs = -(im0 - im1);
        float w = head_w[q];
        C += w * A;
        K[2*q + 0] = w * Bc;
        K[2*q + 1] = w * Bs;
    }
    coef[0] = C;
    coef[1] = K[0]; coef[2] = K[1];
    coef[3] = K[2]; coef[4] = K[3];
}

// ---------------------------------------------------------------------------
// Main: out[b] = C + K0*cos(x0) + K1*sin(x0) + K2*cos(x1) + K3*sin(x1)
// Rows of X are 64 B; we load only cols 0,1 (float2) — one 64 B sector/row is
// the unavoidable HBM granularity.
// ---------------------------------------------------------------------------
__global__ __launch_bounds__(256) void vqc_main(const float* __restrict__ X,
                                                const float* __restrict__ coef,
                                                float* __restrict__ out,
                                                int n)
{
    int b = blockIdx.x * blockDim.x + threadIdx.x;
    if (b >= n) return;
    float C  = coef[0];
    float K0 = coef[1], K1 = coef[2], K2 = coef[3], K3 = coef[4];
    float2 x = *(const float2*)(X + (size_t)b * NQ);
    float s0, c0, s1, c1;
    __sincosf(x.x, &s0, &c0);
    __sincosf(x.y, &s1, &c1);
    out[b] = C + K0 * c0 + K1 * s0 + K2 * c1 + K3 * s1;
}

extern "C" void kernel_launch(void* const* d_in, const int* in_sizes, int n_in,
                              void* d_out, int out_size, void* d_ws, size_t ws_size,
                              hipStream_t stream) {
    const float* X      = (const float*)d_in[0];
    const float* params = (const float*)d_in[1];
    const float* head_w = (const float*)d_in[2];
    const float* head_b = (const float*)d_in[3];
    float* out  = (float*)d_out;
    float* coef = (float*)d_ws;

    vqc_prep<<<1, 64, 0, stream>>>(params, head_w, head_b, coef);

    int threads = 256;
    int blocks  = (out_size + threads - 1) / threads;
    vqc_main<<<blocks, threads, 0, stream>>>(X, coef, out, out_size);
}

// Round 2
// 79.069 us; speedup vs baseline: 1.1403x; 1.1403x over previous
//
#include <hip/hip_runtime.h>
#include <math.h>

#define NQ 16
#define LAYERS 8

// ---------------------------------------------------------------------------
// Prep: fold the 8 Rot layers for qubits 0,1 into closed-form coefficients.
// Parallel version: 16 lanes each build one layer-matrix (fast __sincosf —
// args are ~0.01 rad, error << the 3.75e-2 threshold), 2 lanes fold the
// 8-matrix products (cheap FMAs), lane 0 writes 5 floats.
// ez_q(x) = A + Bc*cos(x) + Bs*sin(x), with U = M7*...*M0:
//   d0 = |u00|^2-|u10|^2, d1 = |u01|^2-|u11|^2
//   A=(d0+d1)/2, Bc=(d0-d1)/2, Bs=-(Im(u00*conj(u01)) - Im(u10*conj(u11)))
// coef[0] = head_b + w0*A0 + w1*A1 ; coef[1..4] = w0*Bc0, w0*Bs0, w1*Bc1, w1*Bs1
// ---------------------------------------------------------------------------
__global__ __launch_bounds__(64) void vqc_prep(
        const float* __restrict__ params,  // [LAYERS][NQ][3]
        const float* __restrict__ head_w,  // [2]
        const float* __restrict__ head_b,  // [1]
        float* __restrict__ coef)          // 5 floats in d_ws
{
    __shared__ float sM[2][LAYERS][8];   // per (q,l): 2x2 complex matrix
    __shared__ float sP[2][3];           // per q: w*A, w*Bc, w*Bs

    int tid = threadIdx.x;
    if (tid < 16) {
        int q = tid >> 3;        // 0..1
        int l = tid & 7;         // 0..7
        float phi = params[(l * NQ + q) * 3 + 0];
        float th  = params[(l * NQ + q) * 3 + 1];
        float om  = params[(l * NQ + q) * 3 + 2];
        float ct, st, c_p, s_p, c_m, s_m;
        __sincosf(0.5f * th, &st, &ct);
        __sincosf(-0.5f * (phi + om), &s_p, &c_p);  // m00 = e^{i*ap} ct
        __sincosf( 0.5f * (phi - om), &s_m, &c_m);  // m10 = e^{-i*am} st
        float* M = sM[q][l];
        M[0] =  c_p * ct;  M[1] =  s_p * ct;   // m00 r,i
        M[2] = -c_m * st;  M[3] = -s_m * st;   // m01 r,i
        M[4] =  c_m * st;  M[5] = -s_m * st;   // m10 r,i
        M[6] =  c_p * ct;  M[7] = -s_p * ct;   // m11 r,i
    }
    __syncthreads();

    if (tid < 2) {
        int q = tid;
        float u00r = 1.f, u00i = 0.f, u01r = 0.f, u01i = 0.f;
        float u10r = 0.f, u10i = 0.f, u11r = 1.f, u11i = 0.f;
        for (int l = 0; l < LAYERS; ++l) {
            const float* M = sM[q][l];
            float m00r = M[0], m00i = M[1], m01r = M[2], m01i = M[3];
            float m10r = M[4], m10i = M[5], m11r = M[6], m11i = M[7];
            float n00r = m00r*u00r - m00i*u00i + m01r*u10r - m01i*u10i;
            float n00i = m00r*u00i + m00i*u00r + m01r*u10i + m01i*u10r;
            float n01r = m00r*u01r - m00i*u01i + m01r*u11r - m01i*u11i;
            float n01i = m00r*u01i + m00i*u01r + m01r*u11i + m01i*u11r;
            float n10r = m10r*u00r - m10i*u00i + m11r*u10r - m11i*u10i;
            float n10i = m10r*u00i + m10i*u00r + m11r*u10i + m11i*u10r;
            float n11r = m10r*u01r - m10i*u01i + m11r*u11r - m11i*u11i;
            float n11i = m10r*u01i + m10i*u01r + m11r*u11i + m11i*u11r;
            u00r = n00r; u00i = n00i; u01r = n01r; u01i = n01i;
            u10r = n10r; u10i = n10i; u11r = n11r; u11i = n11i;
        }
        float d0 = (u00r*u00r + u00i*u00i) - (u10r*u10r + u10i*u10i);
        float d1 = (u01r*u01r + u01i*u01i) - (u11r*u11r + u11i*u11i);
        float A  = 0.5f * (d0 + d1);
        float Bc = 0.5f * (d0 - d1);
        float im0 = u00i*u01r - u00r*u01i;   // Im(u00 * conj(u01))
        float im1 = u10i*u11r - u10r*u11i;   // Im(u10 * conj(u11))
        float Bs = -(im0 - im1);
        float w = head_w[q];
        sP[q][0] = w * A;
        sP[q][1] = w * Bc;
        sP[q][2] = w * Bs;
    }
    __syncthreads();

    if (tid == 0) {
        coef[0] = head_b[0] + sP[0][0] + sP[1][0];
        coef[1] = sP[0][1];
        coef[2] = sP[0][2];
        coef[3] = sP[1][1];
        coef[4] = sP[1][2];
    }
}

// ---------------------------------------------------------------------------
// Main: out[b] = C + K0*cos(x0) + K1*sin(x0) + K2*cos(x1) + K3*sin(x1)
// Rows of X are 64 B; we load only cols 0,1 (float2). Every 64-B sector of X
// contains needed bytes, so FETCH = 32 MiB (whole X) is the structural floor.
// ---------------------------------------------------------------------------
__global__ __launch_bounds__(256) void vqc_main(const float* __restrict__ X,
                                                const float* __restrict__ coef,
                                                float* __restrict__ out,
                                                int n)
{
    int b = blockIdx.x * blockDim.x + threadIdx.x;
    if (b >= n) return;
    float C  = coef[0];
    float K0 = coef[1], K1 = coef[2], K2 = coef[3], K3 = coef[4];
    float2 x = *(const float2*)(X + (size_t)b * NQ);
    float s0, c0, s1, c1;
    __sincosf(x.x, &s0, &c0);
    __sincosf(x.y, &s1, &c1);
    out[b] = C + K0 * c0 + K1 * s0 + K2 * c1 + K3 * s1;
}

extern "C" void kernel_launch(void* const* d_in, const int* in_sizes, int n_in,
                              void* d_out, int out_size, void* d_ws, size_t ws_size,
                              hipStream_t stream) {
    const float* X      = (const float*)d_in[0];
    const float* params = (const float*)d_in[1];
    const float* head_w = (const float*)d_in[2];
    const float* head_b = (const float*)d_in[3];
    float* out  = (float*)d_out;
    float* coef = (float*)d_ws;

    vqc_prep<<<1, 64, 0, stream>>>(params, head_w, head_b, coef);

    int threads = 256;
    int blocks  = (out_size + threads - 1) / threads;
    vqc_main<<<blocks, threads, 0, stream>>>(X, coef, out, out_size);
}

// Round 3
// 78.673 us; speedup vs baseline: 1.1461x; 1.0050x over previous
//
#include <hip/hip_runtime.h>
#include <math.h>

#define NQ 16
#define LAYERS 8

// 2x2 complex matrix in registers.
struct M22 {
    float r00, i00, r01, i01, r10, i10, r11, i11;
};

__device__ __forceinline__ M22 cmul(const M22& A, const M22& B) {
    M22 p;
    p.r00 = A.r00*B.r00 - A.i00*B.i00 + A.r01*B.r10 - A.i01*B.i10;
    p.i00 = A.r00*B.i00 + A.i00*B.r00 + A.r01*B.i10 + A.i01*B.r10;
    p.r01 = A.r00*B.r01 - A.i00*B.i01 + A.r01*B.r11 - A.i01*B.i11;
    p.i01 = A.r00*B.i01 + A.i00*B.r01 + A.r01*B.i11 + A.i01*B.r11;
    p.r10 = A.r10*B.r00 - A.i10*B.i00 + A.r11*B.r10 - A.i11*B.i10;
    p.i10 = A.r10*B.i00 + A.i10*B.r00 + A.r11*B.i10 + A.i11*B.r10;
    p.r11 = A.r10*B.r01 - A.i10*B.i01 + A.r11*B.r11 - A.i11*B.i11;
    p.i11 = A.r10*B.i01 + A.i10*B.r01 + A.r11*B.i11 + A.i11*B.r11;
    return p;
}

__device__ __forceinline__ M22 mshfl_xor(const M22& A, int mask) {
    M22 p;
    p.r00 = __shfl_xor(A.r00, mask); p.i00 = __shfl_xor(A.i00, mask);
    p.r01 = __shfl_xor(A.r01, mask); p.i01 = __shfl_xor(A.i01, mask);
    p.r10 = __shfl_xor(A.r10, mask); p.i10 = __shfl_xor(A.i10, mask);
    p.r11 = __shfl_xor(A.r11, mask); p.i11 = __shfl_xor(A.i11, mask);
    return p;
}

// ---------------------------------------------------------------------------
// Fused kernel. The circuit has no entangling gates, so per readout qubit q:
//   ez_q(x) = A + Bc*cos(x) + Bs*sin(x), with U = M7*...*M0 (2x2 complex):
//     d0=|u00|^2-|u10|^2, d1=|u01|^2-|u11|^2
//     A=(d0+d1)/2, Bc=(d0-d1)/2, Bs=-(Im(u00 conj(u01)) - Im(u10 conj(u11)))
// Wave 0 of each block rebuilds the coefficients (lanes 0-15: one layer
// matrix each via __sincosf — args ~0.01 rad, error << 3.75e-2 threshold;
// 3-step shfl_xor tree folds the 8-matrix product, order preserved).
// All threads' float2 X-loads are issued before the barrier and overlap it.
// out[b] = head_b + w0*ez_0(x0) + w1*ez_1(x1).
// Structural memory floor: cols 0,1 are 8 B of each 64-B row -> whole X
// (32 MiB) must stream from HBM.
// ---------------------------------------------------------------------------
__global__ __launch_bounds__(256) void vqc_fused(
        const float* __restrict__ X,       // [B][NQ]
        const float* __restrict__ params,  // [LAYERS][NQ][3]
        const float* __restrict__ head_w,  // [2]
        const float* __restrict__ head_b,  // [1]
        float* __restrict__ out,           // [B]
        int n)
{
    __shared__ float sC[6];  // w0*A0, w0*Bc0, w0*Bs0, w1*A1, w1*Bc1, w1*Bs1

    int tid = threadIdx.x;
    int b = blockIdx.x * blockDim.x + tid;

    // Issue the global load early; it completes at the barrier's vmcnt wait
    // and overlaps wave 0's coefficient computation.
    float2 x = make_float2(0.f, 0.f);
    if (b < n) x = *(const float2*)(X + (size_t)b * NQ);

    if (tid < 16) {
        int q = tid >> 3;   // 0..1
        int l = tid & 7;    // 0..7
        float phi = params[(l * NQ + q) * 3 + 0];
        float th  = params[(l * NQ + q) * 3 + 1];
        float om  = params[(l * NQ + q) * 3 + 2];
        float ct, st, c_p, s_p, c_m, s_m;
        __sincosf(0.5f * th, &st, &ct);
        __sincosf(-0.5f * (phi + om), &s_p, &c_p);
        __sincosf( 0.5f * (phi - om), &s_m, &c_m);
        M22 U;
        U.r00 =  c_p * ct;  U.i00 =  s_p * ct;
        U.r01 = -c_m * st;  U.i01 = -s_m * st;
        U.r10 =  c_m * st;  U.i10 = -s_m * st;
        U.r11 =  c_p * ct;  U.i11 = -s_p * ct;

        // Tree-fold the product M7*...*M0: partner with higher layer index
        // goes on the LEFT. Masks 1,2,4 stay within each q's 8-lane group.
        #pragma unroll
        for (int mask = 1; mask <= 4; mask <<= 1) {
            M22 other = mshfl_xor(U, mask);
            bool upper = (tid & mask) != 0;
            M22 left  = upper ? U : other;
            M22 right = upper ? other : U;
            U = cmul(left, right);
        }

        if (l == 0) {  // lanes 0 and 8 hold the full product for q=0,1
            float d0 = (U.r00*U.r00 + U.i00*U.i00) - (U.r10*U.r10 + U.i10*U.i10);
            float d1 = (U.r01*U.r01 + U.i01*U.i01) - (U.r11*U.r11 + U.i11*U.i11);
            float A  = 0.5f * (d0 + d1);
            float Bc = 0.5f * (d0 - d1);
            float im0 = U.i00*U.r01 - U.r00*U.i01;  // Im(u00 * conj(u01))
            float im1 = U.i10*U.r11 - U.r10*U.i11;  // Im(u10 * conj(u11))
            float Bs = -(im0 - im1);
            float w = head_w[q];
            sC[3*q + 0] = w * A;
            sC[3*q + 1] = w * Bc;
            sC[3*q + 2] = w * Bs;
        }
    }
    __syncthreads();

    if (b >= n) return;
    float C  = head_b[0] + sC[0] + sC[3];
    float K0 = sC[1], K1 = sC[2], K2 = sC[4], K3 = sC[5];
    float s0, c0, s1, c1;
    __sincosf(x.x, &s0, &c0);
    __sincosf(x.y, &s1, &c1);
    out[b] = C + K0 * c0 + K1 * s0 + K2 * c1 + K3 * s1;
}

extern "C" void kernel_launch(void* const* d_in, const int* in_sizes, int n_in,
                              void* d_out, int out_size, void* d_ws, size_t ws_size,
                              hipStream_t stream) {
    const float* X      = (const float*)d_in[0];
    const float* params = (const float*)d_in[1];
    const float* head_w = (const float*)d_in[2];
    const float* head_b = (const float*)d_in[3];
    float* out = (float*)d_out;

    int threads = 256;
    int blocks  = (out_size + threads - 1) / threads;
    vqc_fused<<<blocks, threads, 0, stream>>>(X, params, head_w, head_b, out, out_size);
}